// Round 6
// baseline (386.536 us; speedup 1.0000x reference)
//
#include <hip/hip_runtime.h>

// Fused cross-attention: out = concat(dec, softmax_e(enc·dec^T)^T-weighted enc)
// B=8, T_enc=T_dec=2048, D=512, fp32 in/out.
// R6: 1024 threads / 16 waves per block (4 waves/SIMD at 128 VGPR, 1 block/CU).
// Wave = (ks = wv>>1: 64-d k-slice, th = wv&1: 32-t half). Same LDS map as R5.
// 2-barrier pipeline: A = QK(ch); B = softmax(ch) ∥ PV(ch-1) ∥ Khi(ch+1) ∥ loads(ch+2);
// C = KT-write(ch) from held regs. T13 defer-max (THR=8).

typedef _Float16 f16;
typedef f16 f16x8 __attribute__((ext_vector_type(8)));
typedef f16 f16x4 __attribute__((ext_vector_type(4)));
typedef f16 f16x2 __attribute__((ext_vector_type(2)));
typedef float f32x4 __attribute__((ext_vector_type(4)));
typedef float f32x2 __attribute__((ext_vector_type(2)));

#define NB 8
#define TE 2048
#define TD 2048
#define DD 512
#define TBLK 64
#define EBLK 32
#define NCH (TE / EBLK)

// LDS layout (bytes) — audited: no overlaps, end = 158592 < 163840
#define OKHI 0          // [32][512] f16 = 32768B, 1024B swizzled rows (QK A-operand)
#define OKT  32768      // [512][40] f16 = 40960B, 80B rows, sig-swizzled (PV A-operand)
#define OS8  73728      // 8 ks x [64 tc][36 er] f32 = 73728B (tc-major partial S)
#define OP   147456     // 2 x [64][40] f16 = 10240B, P[t][e]
#define OPSZ 5120
#define OAL  157696     // 2 x 64 f32 alpha
#define OLL  158208     // 64 f32 l
#define OFLG 158464     // 2 x 16 u32 rescale flags
#define SMEM_BYTES 158592

__device__ __forceinline__ int swz1k(int row, int byteInRow) {
    return row * 1024 + (byteInRow ^ ((row & 7) << 4));
}

__global__ __launch_bounds__(1024, 4)
void attn_fused(const float* __restrict__ enc, const float* __restrict__ dec,
                float* __restrict__ out) {
    __shared__ __align__(16) char sm[SMEM_BYTES];
    const int tid  = threadIdx.x;
    const int b    = blockIdx.x & 7;          // XCD-pinned batch
    const int t0   = (blockIdx.x >> 3) * TBLK;
    const int lane = tid & 63;
    const int wv   = tid >> 6;                // 0..15
    const int ks   = wv >> 1;                 // k-slice 0..7 (d in [64ks, 64ks+64))
    const int th   = wv & 1;                  // t-half (tt = 2th, 2th+1)
    const int li   = lane & 15;
    const int gi   = lane >> 4;
    const float L2E = 1.44269504088896f;

    const float* encB = enc + (size_t)b * TE * DD;
    const float* decB = dec + (size_t)b * TD * DD;
    float*       outB = out + (size_t)b * TD * (2 * DD);

    // staging mapping: thread = (c4 = d-quad 0..127, rb = e-quad-group 0..7)
    const int c4 = tid & 127;
    const int rb = tid >> 7;

    // ---- issue K0 loads (4 rows x float4 per thread) ----
    f32x4 st[4];
    #pragma unroll
    for (int i = 0; i < 4; ++i)
        st[i] = *(const f32x4*)(encB + (size_t)(4 * rb + i) * DD + 4 * c4);

    // ---- Q fragments (hi/lo) direct from global into registers ----
    // wave covers t rows [t0+32th, t0+32th+32), d in [64ks, 64ks+64)
    f16x8 qH[2][2], qL[2][2];
    #pragma unroll
    for (int kk = 0; kk < 2; ++kk)
        #pragma unroll
        for (int tl = 0; tl < 2; ++tl) {
            const float* qp = decB + (size_t)(t0 + 16 * (2 * th + tl) + li) * DD
                            + 64 * ks + 32 * kk + 8 * gi;
            f32x4 q0 = *(const f32x4*)qp;
            f32x4 q1 = *(const f32x4*)(qp + 4);
            f16x8 h, l;
            #pragma unroll
            for (int j = 0; j < 4; ++j) {
                f16 h0 = (f16)q0[j]; h[j]     = h0; l[j]     = (f16)(q0[j] - (float)h0);
                f16 h1 = (f16)q1[j]; h[4 + j] = h1; l[4 + j] = (f16)(q1[j] - (float)h1);
            }
            qH[kk][tl] = h; qL[kk][tl] = l;
        }

    // ---- cvt K0 into hvB + Khi-write(0); KT(0) written in iter 0 phase C ----
    f16x4 hvB[4];
    #pragma unroll
    for (int i = 0; i < 4; ++i) {
        f16x4 h4 = {(f16)st[i][0], (f16)st[i][1], (f16)st[i][2], (f16)st[i][3]};
        hvB[i] = h4;
        *(f16x4*)(sm + OKHI + swz1k(4 * rb + i, 8 * c4)) = h4;
    }
    // issue K1 loads
    #pragma unroll
    for (int i = 0; i < 4; ++i)
        st[i] = *(const f32x4*)(encB + (size_t)(EBLK + 4 * rb + i) * DD + 4 * c4);
    __syncthreads();

    // softmax ownership: wave wv owns t-cols [4wv, 4wv+4); 16 lanes per col
    const int cq   = lane & 3;
    const int erq  = lane >> 2;               // 0..15; lane holds e-rows 2erq, 2erq+1
    const int tcol = 4 * wv + cq;
    float mrun = -1.0e30f, lrun = 0.0f;

    f32x4 ctx[2][4];                          // d-slice [32wv, 32wv+32): 2 md x 4 tt
    #pragma unroll
    for (int md = 0; md < 2; ++md)
        #pragma unroll
        for (int tt = 0; tt < 4; ++tt)
            ctx[md][tt] = (f32x4){0.f, 0.f, 0.f, 0.f};

    for (int ch = 0; ch < NCH; ++ch) {
        const int pb = ch & 1;
        const int qb = pb ^ 1;
        const bool doPV = (ch > 0);
        const bool more = (ch + 1 < NCH);

        // ---- phase A: QK(ch), S8 partial writes ----
        f32x4 sacc[2][2];
        #pragma unroll
        for (int et = 0; et < 2; ++et)
            #pragma unroll
            for (int tl = 0; tl < 2; ++tl)
                sacc[et][tl] = (f32x4){0.f, 0.f, 0.f, 0.f};
        __builtin_amdgcn_s_setprio(1);
        #pragma unroll
        for (int kk = 0; kk < 2; ++kk) {
            int cb = 2 * (64 * ks + 32 * kk) + 16 * gi;
            f16x8 aF[2];
            #pragma unroll
            for (int et = 0; et < 2; ++et)
                aF[et] = *(const f16x8*)(sm + OKHI + swz1k(16 * et + li, cb));
            #pragma unroll
            for (int et = 0; et < 2; ++et)
                #pragma unroll
                for (int tl = 0; tl < 2; ++tl) {
                    sacc[et][tl] = __builtin_amdgcn_mfma_f32_16x16x32_f16(aF[et], qH[kk][tl], sacc[et][tl], 0, 0, 0);
                    sacc[et][tl] = __builtin_amdgcn_mfma_f32_16x16x32_f16(aF[et], qL[kk][tl], sacc[et][tl], 0, 0, 0);
                }
        }
        __builtin_amdgcn_s_setprio(0);
        #pragma unroll
        for (int et = 0; et < 2; ++et)
            #pragma unroll
            for (int tl = 0; tl < 2; ++tl)
                *(f32x4*)(sm + OS8 + ks * 9216 + (16 * (2 * th + tl) + li) * 144 + 64 * et + 16 * gi) = sacc[et][tl];
        __syncthreads();                                   // B1

        // ---- phase B: softmax(ch) ∥ PV(ch-1) ∥ Khi(ch+1) ∥ loads(ch+2) ----
        bool doR = false;
        f16x8 bP[4];
        if (doPV) {
            const uint4* fp = (const uint4*)(sm + OFLG + 64 * qb);
            uint4 f0 = fp[0], f1 = fp[1], f2 = fp[2], f3 = fp[3];
            doR = (f0.x | f0.y | f0.z | f0.w | f1.x | f1.y | f1.z | f1.w |
                   f2.x | f2.y | f2.z | f2.w | f3.x | f3.y | f3.z | f3.w) != 0;
            #pragma unroll
            for (int tt = 0; tt < 4; ++tt)
                bP[tt] = *(const f16x8*)(sm + OP + OPSZ * qb + (16 * tt + li) * 80 + 16 * gi);
        }
        // softmax(ch): lane covers e-rows 2erq, 2erq+1 of its col
        {
            f32x2 s2 = (f32x2){0.f, 0.f};
            #pragma unroll
            for (int bu = 0; bu < 8; ++bu)
                s2 += *(const f32x2*)(sm + OS8 + bu * 9216 + tcol * 144 + 8 * erq);
            float pm = fmaxf(s2[0], s2[1]);
            pm = fmaxf(pm, __shfl_xor(pm, 4));
            pm = fmaxf(pm, __shfl_xor(pm, 8));
            pm = fmaxf(pm, __shfl_xor(pm, 16));
            pm = fmaxf(pm, __shfl_xor(pm, 32));
            bool needc = pm > mrun + 8.0f;                 // T13 defer-max, THR=8
            unsigned long long bal = __ballot(needc);
            if (lane == 0) *(unsigned*)(sm + OFLG + 64 * pb + 4 * wv) = (bal != 0ULL) ? 1u : 0u;
            float mnew  = needc ? pm : mrun;
            float alpha = needc ? exp2f((mrun - mnew) * L2E) : 1.0f;
            float p0 = exp2f((s2[0] - mnew) * L2E);
            float p1 = exp2f((s2[1] - mnew) * L2E);
            float ps = p0 + p1;
            ps += __shfl_xor(ps, 4);
            ps += __shfl_xor(ps, 8);
            ps += __shfl_xor(ps, 16);
            ps += __shfl_xor(ps, 32);
            lrun = lrun * alpha + ps;
            mrun = mnew;
            f16x2 pw = {(f16)p0, (f16)p1};
            *(f16x2*)(sm + OP + OPSZ * pb + tcol * 80 + 4 * erq) = pw;
            if (erq == 0) *(float*)(sm + OAL + 256 * pb + 4 * tcol) = alpha;
        }
        // PV(ch-1) — KT holds chunk ch-1
        if (doPV) {
            if (doR) {
                float av[4];
                #pragma unroll
                for (int tt = 0; tt < 4; ++tt)
                    av[tt] = *(const float*)(sm + OAL + 256 * qb + 4 * (16 * tt + li));
                #pragma unroll
                for (int md = 0; md < 2; ++md)
                    #pragma unroll
                    for (int tt = 0; tt < 4; ++tt)
                        #pragma unroll
                        for (int r = 0; r < 4; ++r) ctx[md][tt][r] *= av[tt];
            }
            __builtin_amdgcn_s_setprio(1);
            #pragma unroll
            for (int md = 0; md < 2; ++md) {
                int dv = 32 * wv + 16 * md + li;
                int sig = ((dv >> 3) & 3) << 4;
                f16x8 a = *(const f16x8*)(sm + OKT + dv * 80 + ((16 * gi) ^ sig));
                #pragma unroll
                for (int tt = 0; tt < 4; ++tt)
                    ctx[md][tt] = __builtin_amdgcn_mfma_f32_16x16x32_f16(a, bP[tt], ctx[md][tt], 0, 0, 0);
            }
            __builtin_amdgcn_s_setprio(0);
        }
        // cvt st(ch+1) -> hvA + Khi-write(ch+1); issue loads(ch+2)
        f16x4 hvA[4];
        if (more) {
            #pragma unroll
            for (int i = 0; i < 4; ++i) {
                f16x4 h4 = {(f16)st[i][0], (f16)st[i][1], (f16)st[i][2], (f16)st[i][3]};
                hvA[i] = h4;
                *(f16x4*)(sm + OKHI + swz1k(4 * rb + i, 8 * c4)) = h4;
            }
            if (ch + 2 < NCH) {
                const float* src = encB + (size_t)(ch + 2) * EBLK * DD;
                #pragma unroll
                for (int i = 0; i < 4; ++i)
                    st[i] = *(const f32x4*)(src + (size_t)(4 * rb + i) * DD + 4 * c4);
            }
        }
        __syncthreads();                                   // B2
        // ---- phase C: KT-write(ch) from hvB ----
        #pragma unroll
        for (int k = 0; k < 4; ++k) {
            int d = 4 * c4 + k;
            int sig = ((d >> 3) & 3) << 4;
            f16x4 q4 = {hvB[0][k], hvB[1][k], hvB[2][k], hvB[3][k]};
            *(f16x4*)(sm + OKT + d * 80 + ((8 * rb) ^ sig)) = q4;
        }
        if (more) {
            #pragma unroll
            for (int i = 0; i < 4; ++i) hvB[i] = hvA[i];
        }
    }

    __syncthreads();   // KT(NCH-1) written in last phase C

    // ---- final PV(NCH-1) ----
    {
        const int qb2 = (NCH - 1) & 1;
        const uint4* fp = (const uint4*)(sm + OFLG + 64 * qb2);
        uint4 f0 = fp[0], f1 = fp[1], f2 = fp[2], f3 = fp[3];
        bool doR = (f0.x | f0.y | f0.z | f0.w | f1.x | f1.y | f1.z | f1.w |
                    f2.x | f2.y | f2.z | f2.w | f3.x | f3.y | f3.z | f3.w) != 0;
        f16x8 bP[4];
        #pragma unroll
        for (int tt = 0; tt < 4; ++tt)
            bP[tt] = *(const f16x8*)(sm + OP + OPSZ * qb2 + (16 * tt + li) * 80 + 16 * gi);
        if (doR) {
            float av[4];
            #pragma unroll
            for (int tt = 0; tt < 4; ++tt)
                av[tt] = *(const float*)(sm + OAL + 256 * qb2 + 4 * (16 * tt + li));
            #pragma unroll
            for (int md = 0; md < 2; ++md)
                #pragma unroll
                for (int tt = 0; tt < 4; ++tt)
                    #pragma unroll
                    for (int r = 0; r < 4; ++r) ctx[md][tt][r] *= av[tt];
        }
        #pragma unroll
        for (int md = 0; md < 2; ++md) {
            int dv = 32 * wv + 16 * md + li;
            int sig = ((dv >> 3) & 3) << 4;
            f16x8 a = *(const f16x8*)(sm + OKT + dv * 80 + ((16 * gi) ^ sig));
            #pragma unroll
            for (int tt = 0; tt < 4; ++tt)
                ctx[md][tt] = __builtin_amdgcn_mfma_f32_16x16x32_f16(a, bP[tt], ctx[md][tt], 0, 0, 0);
        }
    }

    // ---- epilogue: l-normalize + context writes + dec passthrough ----
    if (erq == 0) *(float*)(sm + OLL + 4 * tcol) = lrun;
    __syncthreads();
    float inv[4];
    #pragma unroll
    for (int tt = 0; tt < 4; ++tt)
        inv[tt] = 1.0f / *(const float*)(sm + OLL + 4 * (16 * tt + li));
    #pragma unroll
    for (int md = 0; md < 2; ++md)
        #pragma unroll
        for (int tt = 0; tt < 4; ++tt) {
            int t = t0 + 16 * tt + li;
            int d = 32 * wv + 16 * md + 4 * gi;
            float4 o;
            o.x = ctx[md][tt][0] * inv[tt];
            o.y = ctx[md][tt][1] * inv[tt];
            o.z = ctx[md][tt][2] * inv[tt];
            o.w = ctx[md][tt][3] * inv[tt];
            *(float4*)(outB + (size_t)t * (2 * DD) + DD + d) = o;
        }
    #pragma unroll
    for (int it = 0; it < TBLK * (DD / 4) / 1024; ++it) {
        int i = tid + it * 1024;
        int t = i >> 7, cc = i & 127;
        float4 q = ((const float4*)(decB + (size_t)(t0 + t) * DD))[cc];
        ((float4*)(outB + (size_t)(t0 + t) * (2 * DD)))[cc] = q;
    }
}

extern "C" void kernel_launch(void* const* d_in, const int* in_sizes, int n_in,
                              void* d_out, int out_size, void* d_ws, size_t ws_size,
                              hipStream_t stream) {
    const float* enc = (const float*)d_in[0];
    const float* dec = (const float*)d_in[1];
    float* out = (float*)d_out;
    dim3 grid(NB * (TD / TBLK));   // 256 blocks: b = bid&7 (XCD pin), ttile = bid>>3
    dim3 block(1024);
    attn_fused<<<grid, block, 0, stream>>>(enc, dec, out);
}

// Round 7
// 322.853 us; speedup vs baseline: 1.1973x; 1.1973x over previous
//
#include <hip/hip_runtime.h>

// Fused cross-attention: out = concat(dec, softmax_e(enc·dec^T)^T-weighted enc)
// B=8, T_enc=T_dec=2048, D=512, fp32 in/out.
// R7: TBLK=32, 512 threads, LDS 77.6KB -> 2 blocks/CU (4 waves/SIMD).
// QK in plain f16 (fp32 MFMA accum), k-split-2: wave = (tq,eq,kh).
// 3-barrier loop: A = KT-w(ch) ∥ QK(ch); S = softmax(ch) ∥ issue loads(ch+1);
// P = PV(ch) ∥ cvt+Khi-w(ch+1). Single-buffered KT/P/alpha/flags.
// T13 defer-max (THR=8), XCD-pinned batch.

typedef _Float16 f16;
typedef f16 f16x8 __attribute__((ext_vector_type(8)));
typedef f16 f16x4 __attribute__((ext_vector_type(4)));
typedef f16 f16x2 __attribute__((ext_vector_type(2)));
typedef float f32x4 __attribute__((ext_vector_type(4)));
typedef float f32x2 __attribute__((ext_vector_type(2)));

#define NB 8
#define TE 2048
#define TD 2048
#define DD 512
#define TBLK 32
#define EBLK 32
#define NCH (TE / EBLK)

// LDS layout (bytes) — audited: end 77600 <= 81920 (2 blocks/CU)
#define OKHI 0          // [32 e][512 d] f16 = 32768B, 1024B swizzled rows (QK A)
#define OKT  32768      // [512 d][32 e] f16 = 32768B, 64B rows, 16B-granule XOR (PV A)
#define OS2  65536      // [2 kh][32 tc][36 er] f32 = 9216B (144B rows)
#define OP   74752      // [32 tc][40 e] f16 = 2560B, 80B rows
#define OAL  77312      // 32 f32 alpha
#define OLL  77440      // 32 f32 l
#define OFLG 77568      // 8 u32 rescale flags
#define SMEM_BYTES 77600

__device__ __forceinline__ int swz1k(int row, int b) {
    return row * 1024 + (b ^ ((row & 7) << 4));
}
__device__ __forceinline__ int ktadr(int d, int b) {
    return OKT + d * 64 + (b ^ (((d >> 2) & 3) << 4));
}

__global__ __launch_bounds__(512, 4)
void attn_fused(const float* __restrict__ enc, const float* __restrict__ dec,
                float* __restrict__ out) {
    __shared__ __align__(16) char sm[SMEM_BYTES];
    const int tid  = threadIdx.x;
    const int b    = blockIdx.x & 7;          // XCD-pinned batch
    const int t0   = (blockIdx.x >> 3) * TBLK;
    const int lane = tid & 63;
    const int wv   = tid >> 6;
    const int li   = lane & 15;
    const int gi   = lane >> 4;
    const int kh   = wv >> 2;                 // k-half: d in [256kh, 256kh+256)
    const int tq   = (wv >> 1) & 1;           // t-tile
    const int eq   = wv & 1;                  // e-tile
    const float L2E = 1.44269504088896f;

    const float* encB = enc + (size_t)b * TE * DD;
    const float* decB = dec + (size_t)b * TD * DD;
    float*       outB = out + (size_t)b * TD * (2 * DD);

    // staging map: c4 = d-quad 0..127, rb = e-octet 0..3 (e rows 8rb..8rb+7)
    const int c4 = tid & 127;
    const int rb = tid >> 7;

    // ---- issue K0 loads ----
    f32x4 st[8];
    #pragma unroll
    for (int i = 0; i < 8; ++i)
        st[i] = *(const f32x4*)(encB + (size_t)(8 * rb + i) * DD + 4 * c4);

    // ---- Q fragments (f16) direct from global: t = t0+16tq+li, k-half kh ----
    f16x8 qF[8];
    #pragma unroll
    for (int kk = 0; kk < 8; ++kk) {
        const float* qp = decB + (size_t)(t0 + 16 * tq + li) * DD + 256 * kh + 32 * kk + 8 * gi;
        f32x4 q0 = *(const f32x4*)qp;
        f32x4 q1 = *(const f32x4*)(qp + 4);
        f16x8 h;
        #pragma unroll
        for (int j = 0; j < 4; ++j) { h[j] = (f16)q0[j]; h[4 + j] = (f16)q1[j]; }
        qF[kk] = h;
    }

    // ---- cvt K0 -> hv, Khi-write(0); KT-w(0) happens in A(0) ----
    f16x4 hv[8];
    #pragma unroll
    for (int i = 0; i < 8; ++i) {
        f16x4 h4 = {(f16)st[i][0], (f16)st[i][1], (f16)st[i][2], (f16)st[i][3]};
        hv[i] = h4;
        *(f16x4*)(sm + OKHI + swz1k(8 * rb + i, 8 * c4)) = h4;
    }
    __syncthreads();

    // softmax ownership: wave owns t-cols [4wv,4wv+4); 16 lanes/col, 2 e-rows/lane
    const int cq   = lane & 3;
    const int erq  = lane >> 2;               // 0..15 -> e rows 2erq, 2erq+1
    const int tcol = 4 * wv + cq;
    float mrun = -1.0e30f, lrun = 0.0f;

    f32x4 ctx[4][2];                          // d-slice [64wv,64wv+64) x 32 t
    #pragma unroll
    for (int md = 0; md < 4; ++md) {
        ctx[md][0] = (f32x4){0.f, 0.f, 0.f, 0.f};
        ctx[md][1] = (f32x4){0.f, 0.f, 0.f, 0.f};
    }

    for (int ch = 0; ch < NCH; ++ch) {
        const bool more = (ch + 1 < NCH);
        // ---- phase A: KT-write(ch) from hv ∥ QK(ch) ----
        #pragma unroll
        for (int k = 0; k < 4; ++k) {
            int d = 4 * c4 + k;
            f16x8 q8 = {hv[0][k], hv[1][k], hv[2][k], hv[3][k],
                        hv[4][k], hv[5][k], hv[6][k], hv[7][k]};
            *(f16x8*)(sm + ktadr(d, 16 * rb)) = q8;
        }
        f32x4 sacc = (f32x4){0.f, 0.f, 0.f, 0.f};
        __builtin_amdgcn_s_setprio(1);
        #pragma unroll
        for (int kk = 0; kk < 8; ++kk) {
            f16x8 aF = *(const f16x8*)(sm + OKHI + swz1k(16 * eq + li, 512 * kh + 64 * kk + 16 * gi));
            sacc = __builtin_amdgcn_mfma_f32_16x16x32_f16(aF, qF[kk], sacc, 0, 0, 0);
        }
        __builtin_amdgcn_s_setprio(0);
        *(f32x4*)(sm + OS2 + kh * 4608 + (16 * tq + li) * 144 + (16 * eq + 4 * gi) * 4) = sacc;
        __syncthreads();                                   // B1

        // ---- phase S: issue loads(ch+1) ∥ softmax(ch) ----
        if (more) {
            const float* src = encB + (size_t)(ch + 1) * EBLK * DD;
            #pragma unroll
            for (int i = 0; i < 8; ++i)
                st[i] = *(const f32x4*)(src + (size_t)(8 * rb + i) * DD + 4 * c4);
        }
        {
            f32x2 a0 = *(const f32x2*)(sm + OS2 + tcol * 144 + 8 * erq);
            f32x2 a1 = *(const f32x2*)(sm + OS2 + 4608 + tcol * 144 + 8 * erq);
            float s0 = a0[0] + a1[0];
            float s1 = a0[1] + a1[1];
            float pm = fmaxf(s0, s1);
            pm = fmaxf(pm, __shfl_xor(pm, 4));
            pm = fmaxf(pm, __shfl_xor(pm, 8));
            pm = fmaxf(pm, __shfl_xor(pm, 16));
            pm = fmaxf(pm, __shfl_xor(pm, 32));
            bool needc = pm > mrun + 8.0f;                 // T13 defer-max
            unsigned long long bal = __ballot(needc);
            if (lane == 0) *(unsigned*)(sm + OFLG + 4 * wv) = (bal != 0ULL) ? 1u : 0u;
            float mnew  = needc ? pm : mrun;
            float alpha = needc ? exp2f((mrun - mnew) * L2E) : 1.0f;
            float p0 = exp2f((s0 - mnew) * L2E);
            float p1 = exp2f((s1 - mnew) * L2E);
            float ps = p0 + p1;
            ps += __shfl_xor(ps, 4);
            ps += __shfl_xor(ps, 8);
            ps += __shfl_xor(ps, 16);
            ps += __shfl_xor(ps, 32);
            lrun = lrun * alpha + ps;
            mrun = mnew;
            f16x2 pw = {(f16)p0, (f16)p1};
            *(f16x2*)(sm + OP + tcol * 80 + 4 * erq) = pw;
            if (erq == 0) *(float*)(sm + OAL + 4 * tcol) = alpha;
        }
        __syncthreads();                                   // B2

        // ---- phase P: PV(ch) ∥ cvt + Khi-write(ch+1) ----
        {
            const uint4* fp = (const uint4*)(sm + OFLG);
            uint4 f0 = fp[0], f1 = fp[1];
            bool doR = (f0.x | f0.y | f0.z | f0.w | f1.x | f1.y | f1.z | f1.w) != 0;
            f16x8 bP[2];
            #pragma unroll
            for (int tt = 0; tt < 2; ++tt)
                bP[tt] = *(const f16x8*)(sm + OP + (16 * tt + li) * 80 + 16 * gi);
            if (doR) {
                float av[2];
                #pragma unroll
                for (int tt = 0; tt < 2; ++tt)
                    av[tt] = *(const float*)(sm + OAL + 4 * (16 * tt + li));
                #pragma unroll
                for (int md = 0; md < 4; ++md)
                    #pragma unroll
                    for (int tt = 0; tt < 2; ++tt)
                        #pragma unroll
                        for (int r = 0; r < 4; ++r) ctx[md][tt][r] *= av[tt];
            }
            __builtin_amdgcn_s_setprio(1);
            #pragma unroll
            for (int md = 0; md < 4; ++md) {
                int dv = 64 * wv + 16 * md + li;
                f16x8 aV = *(const f16x8*)(sm + ktadr(dv, 16 * gi));
                #pragma unroll
                for (int tt = 0; tt < 2; ++tt)
                    ctx[md][tt] = __builtin_amdgcn_mfma_f32_16x16x32_f16(aV, bP[tt], ctx[md][tt], 0, 0, 0);
            }
            __builtin_amdgcn_s_setprio(0);
        }
        if (more) {
            #pragma unroll
            for (int i = 0; i < 8; ++i) {
                f16x4 h4 = {(f16)st[i][0], (f16)st[i][1], (f16)st[i][2], (f16)st[i][3]};
                hv[i] = h4;
                *(f16x4*)(sm + OKHI + swz1k(8 * rb + i, 8 * c4)) = h4;
            }
        }
        __syncthreads();                                   // B3
    }

    // ---- epilogue: l-normalize + context writes + dec passthrough ----
    if (erq == 0) *(float*)(sm + OLL + 4 * tcol) = lrun;
    __syncthreads();
    float inv[2];
    #pragma unroll
    for (int tt = 0; tt < 2; ++tt)
        inv[tt] = 1.0f / *(const float*)(sm + OLL + 4 * (16 * tt + li));
    #pragma unroll
    for (int md = 0; md < 4; ++md)
        #pragma unroll
        for (int tt = 0; tt < 2; ++tt) {
            int t = t0 + 16 * tt + li;
            int d = 64 * wv + 16 * md + 4 * gi;
            float4 o;
            o.x = ctx[md][tt][0] * inv[tt];
            o.y = ctx[md][tt][1] * inv[tt];
            o.z = ctx[md][tt][2] * inv[tt];
            o.w = ctx[md][tt][3] * inv[tt];
            *(float4*)(outB + (size_t)t * (2 * DD) + DD + d) = o;
        }
    #pragma unroll
    for (int it = 0; it < TBLK * (DD / 4) / 512; ++it) {
        int i = tid + it * 512;
        int t = i >> 7, cc = i & 127;
        float4 q = ((const float4*)(decB + (size_t)(t0 + t) * DD))[cc];
        ((float4*)(outB + (size_t)(t0 + t) * (2 * DD)))[cc] = q;
    }
}

extern "C" void kernel_launch(void* const* d_in, const int* in_sizes, int n_in,
                              void* d_out, int out_size, void* d_ws, size_t ws_size,
                              hipStream_t stream) {
    const float* enc = (const float*)d_in[0];
    const float* dec = (const float*)d_in[1];
    float* out = (float*)d_out;
    dim3 grid(NB * (TD / TBLK));   // 512 blocks = 2/CU; b = bid&7 (XCD pin)
    dim3 block(512);
    attn_fused<<<grid, block, 0, stream>>>(enc, dec, out);
}

// Round 8
// 145.115 us; speedup vs baseline: 2.6637x; 2.2248x over previous
//
#include <hip/hip_runtime.h>

// Fused cross-attention: out = concat(dec, softmax_e(enc·dec^T)^T-weighted enc)
// B=8, T_enc=T_dec=2048, D=512, fp32 in/out.
// R8: R5 skeleton (TBLK=64, 512 thr, 1 blk/CU, 2 waves/SIMD, 256-reg budget),
//     f16-only QK (R7-validated accuracy), k-split 4 (wave = tq x kq),
//     S4 merge (36KB), softmax 8 cols/wave. 2-barrier pipeline with
//     deferred KT-write and T13 defer-max (THR=8).

typedef _Float16 f16;
typedef f16 f16x8 __attribute__((ext_vector_type(8)));
typedef f16 f16x4 __attribute__((ext_vector_type(4)));
typedef float f32x4 __attribute__((ext_vector_type(4)));

#define NB 8
#define TE 2048
#define TD 2048
#define DD 512
#define TBLK 64
#define EBLK 32
#define NCH (TE / EBLK)

// LDS layout (bytes) — audited: end 121664 < 163840
#define OKHI 0          // [32 e][512 d] f16 = 32768B, 1024B swizzled rows (QK A)
#define OKT  32768      // [512 d][40 e] f16 = 40960B, 80B rows, sig-swizzled (PV A)
#define OS4  73728      // 4 kq x [64 t][36 e] f32 = 36864B (144B rows)
#define OP   110592     // 2 x [64 t][40 e] f16 = 10240B, 80B rows
#define OPSZ 5120
#define OAL  120832     // 2 x 64 f32 alpha
#define OLL  121344     // 64 f32 l
#define OFLG 121600     // 2 x 8 u32 rescale flags
#define SMEM_BYTES 121664

__device__ __forceinline__ int swz1k(int row, int byteInRow) {
    return row * 1024 + (byteInRow ^ ((row & 7) << 4));
}

__global__ __launch_bounds__(512, 2)
void attn_fused(const float* __restrict__ enc, const float* __restrict__ dec,
                float* __restrict__ out) {
    __shared__ __align__(16) char sm[SMEM_BYTES];
    const int tid  = threadIdx.x;
    const int b    = blockIdx.x & 7;          // XCD-pinned batch
    const int t0   = (blockIdx.x >> 3) * TBLK;
    const int lane = tid & 63;
    const int wv   = tid >> 6;
    const int li   = lane & 15;
    const int gi   = lane >> 4;
    const int tq   = wv & 1;                  // t-half: rows 32tq..32tq+31
    const int kq   = wv >> 1;                 // k-slice: d in [128kq, 128kq+128)
    const float L2E = 1.44269504088896f;

    const float* encB = enc + (size_t)b * TE * DD;
    const float* decB = dec + (size_t)b * TD * DD;
    float*       outB = out + (size_t)b * TD * (2 * DD);

    // staging map: c4 = d-quad 0..127, rb = e-octet 0..3 (e rows 8rb..8rb+7)
    const int c4 = tid & 127;
    const int rb = tid >> 7;

    // ---- issue K0 loads ----
    f32x4 st[8];
    #pragma unroll
    for (int i = 0; i < 8; ++i)
        st[i] = *(const f32x4*)(encB + (size_t)(8 * rb + i) * DD + 4 * c4);

    // ---- Q fragments (f16) direct from global ----
    // frag (kk, tl): t-row = t0+32tq+16tl+li, d = 128kq+32kk+8gi+0..7
    f16x8 qF[4][2];
    #pragma unroll
    for (int kk = 0; kk < 4; ++kk)
        #pragma unroll
        for (int tl = 0; tl < 2; ++tl) {
            const float* qp = decB + (size_t)(t0 + 32 * tq + 16 * tl + li) * DD
                            + 128 * kq + 32 * kk + 8 * gi;
            f32x4 q0 = *(const f32x4*)qp;
            f32x4 q1 = *(const f32x4*)(qp + 4);
            f16x8 h;
            #pragma unroll
            for (int j = 0; j < 4; ++j) { h[j] = (f16)q0[j]; h[4 + j] = (f16)q1[j]; }
            qF[kk][tl] = h;
        }

    // ---- cvt K0 -> hvB + Khi-write(0); KT(0) written in iter 0 phase C ----
    f16x4 hvB[8];
    #pragma unroll
    for (int i = 0; i < 8; ++i) {
        f16x4 h4 = {(f16)st[i][0], (f16)st[i][1], (f16)st[i][2], (f16)st[i][3]};
        hvB[i] = h4;
        *(f16x4*)(sm + OKHI + swz1k(8 * rb + i, 8 * c4)) = h4;
    }
    // issue K1 loads
    #pragma unroll
    for (int i = 0; i < 8; ++i)
        st[i] = *(const f32x4*)(encB + (size_t)(EBLK + 8 * rb + i) * DD + 4 * c4);
    __syncthreads();

    // softmax ownership: wave owns t-cols [8wv, 8wv+8); 8 lanes/col, 4 e/lane
    const int cq   = lane & 7;
    const int erq  = lane >> 3;               // 0..7 -> e rows 4erq..4erq+3
    const int tcol = 8 * wv + cq;
    float mrun = -1.0e30f, lrun = 0.0f;

    f32x4 ctx[4][4];                          // d [64wv,64wv+64) x t [0,64)
    #pragma unroll
    for (int md = 0; md < 4; ++md)
        #pragma unroll
        for (int tt = 0; tt < 4; ++tt)
            ctx[md][tt] = (f32x4){0.f, 0.f, 0.f, 0.f};

    for (int ch = 0; ch < NCH; ++ch) {
        const int pb = ch & 1;
        const int qb = pb ^ 1;
        const bool doPV = (ch > 0);
        const bool more = (ch + 1 < NCH);

        // ---- phase A: QK(ch), S4 partial writes ----
        f32x4 sacc[2][2];
        #pragma unroll
        for (int et = 0; et < 2; ++et)
            #pragma unroll
            for (int tl = 0; tl < 2; ++tl)
                sacc[et][tl] = (f32x4){0.f, 0.f, 0.f, 0.f};
        __builtin_amdgcn_s_setprio(1);
        #pragma unroll
        for (int kk = 0; kk < 4; ++kk) {
            int cb = 256 * kq + 64 * kk + 16 * gi;
            f16x8 aF[2];
            #pragma unroll
            for (int et = 0; et < 2; ++et)
                aF[et] = *(const f16x8*)(sm + OKHI + swz1k(16 * et + li, cb));
            #pragma unroll
            for (int et = 0; et < 2; ++et)
                #pragma unroll
                for (int tl = 0; tl < 2; ++tl)
                    sacc[et][tl] = __builtin_amdgcn_mfma_f32_16x16x32_f16(aF[et], qF[kk][tl], sacc[et][tl], 0, 0, 0);
        }
        __builtin_amdgcn_s_setprio(0);
        #pragma unroll
        for (int et = 0; et < 2; ++et)
            #pragma unroll
            for (int tl = 0; tl < 2; ++tl)
                *(f32x4*)(sm + OS4 + kq * 9216 + (32 * tq + 16 * tl + li) * 144
                          + (16 * et + 4 * gi) * 4) = sacc[et][tl];
        __syncthreads();                                   // B1

        // ---- phase B: softmax(ch) ∥ PV(ch-1) ∥ Khi(ch+1) ∥ loads(ch+2) ----
        bool doR = false;
        f16x8 bP[4];
        if (doPV) {
            const uint4* fp = (const uint4*)(sm + OFLG + 32 * qb);
            uint4 f0 = fp[0], f1 = fp[1];
            doR = (f0.x | f0.y | f0.z | f0.w | f1.x | f1.y | f1.z | f1.w) != 0;
            #pragma unroll
            for (int tt = 0; tt < 4; ++tt)
                bP[tt] = *(const f16x8*)(sm + OP + OPSZ * qb + (16 * tt + li) * 80 + 16 * gi);
        }
        // softmax(ch): lane covers e 4erq..4erq+3 of col tcol
        {
            f32x4 s4 = (f32x4){0.f, 0.f, 0.f, 0.f};
            #pragma unroll
            for (int bu = 0; bu < 4; ++bu)
                s4 += *(const f32x4*)(sm + OS4 + bu * 9216 + tcol * 144 + 16 * erq);
            float pm = fmaxf(fmaxf(s4[0], s4[1]), fmaxf(s4[2], s4[3]));
            pm = fmaxf(pm, __shfl_xor(pm, 8));
            pm = fmaxf(pm, __shfl_xor(pm, 16));
            pm = fmaxf(pm, __shfl_xor(pm, 32));
            bool needc = pm > mrun + 8.0f;                 // T13 defer-max
            unsigned long long bal = __ballot(needc);
            if (lane == 0) *(unsigned*)(sm + OFLG + 32 * pb + 4 * wv) = (bal != 0ULL) ? 1u : 0u;
            float mnew  = needc ? pm : mrun;
            float alpha = needc ? exp2f((mrun - mnew) * L2E) : 1.0f;
            f32x4 p4;
            #pragma unroll
            for (int j = 0; j < 4; ++j) p4[j] = exp2f((s4[j] - mnew) * L2E);
            float ps = p4[0] + p4[1] + p4[2] + p4[3];
            ps += __shfl_xor(ps, 8);
            ps += __shfl_xor(ps, 16);
            ps += __shfl_xor(ps, 32);
            lrun = lrun * alpha + ps;
            mrun = mnew;
            f16x4 pw = {(f16)p4[0], (f16)p4[1], (f16)p4[2], (f16)p4[3]};
            *(f16x4*)(sm + OP + OPSZ * pb + tcol * 80 + 8 * erq) = pw;
            if (erq == 0) *(float*)(sm + OAL + 256 * pb + 4 * tcol) = alpha;
        }
        // PV(ch-1): KT holds chunk ch-1 (written in phase C of iter ch-1)
        if (doPV) {
            if (doR) {
                float av[4];
                #pragma unroll
                for (int tt = 0; tt < 4; ++tt)
                    av[tt] = *(const float*)(sm + OAL + 256 * qb + 4 * (16 * tt + li));
                #pragma unroll
                for (int md = 0; md < 4; ++md)
                    #pragma unroll
                    for (int tt = 0; tt < 4; ++tt)
                        #pragma unroll
                        for (int r = 0; r < 4; ++r) ctx[md][tt][r] *= av[tt];
            }
            __builtin_amdgcn_s_setprio(1);
            #pragma unroll
            for (int md = 0; md < 4; ++md) {
                int dv = 64 * wv + 16 * md + li;
                int sig = ((dv >> 3) & 3) << 4;
                f16x8 a = *(const f16x8*)(sm + OKT + dv * 80 + ((16 * gi) ^ sig));
                #pragma unroll
                for (int tt = 0; tt < 4; ++tt)
                    ctx[md][tt] = __builtin_amdgcn_mfma_f32_16x16x32_f16(a, bP[tt], ctx[md][tt], 0, 0, 0);
            }
            __builtin_amdgcn_s_setprio(0);
        }
        // cvt st(ch+1) -> hvA + Khi-write(ch+1); issue loads(ch+2)
        f16x4 hvA[8];
        if (more) {
            #pragma unroll
            for (int i = 0; i < 8; ++i) {
                f16x4 h4 = {(f16)st[i][0], (f16)st[i][1], (f16)st[i][2], (f16)st[i][3]};
                hvA[i] = h4;
                *(f16x4*)(sm + OKHI + swz1k(8 * rb + i, 8 * c4)) = h4;
            }
            if (ch + 2 < NCH) {
                const float* src = encB + (size_t)(ch + 2) * EBLK * DD;
                #pragma unroll
                for (int i = 0; i < 8; ++i)
                    st[i] = *(const f32x4*)(src + (size_t)(8 * rb + i) * DD + 4 * c4);
            }
        }
        __syncthreads();                                   // B2
        // ---- phase C: KT-write(ch) from hvB ----
        #pragma unroll
        for (int k = 0; k < 4; ++k) {
            int d = 4 * c4 + k;
            int sig = ((d >> 3) & 3) << 4;
            f16x8 q8 = {hvB[0][k], hvB[1][k], hvB[2][k], hvB[3][k],
                        hvB[4][k], hvB[5][k], hvB[6][k], hvB[7][k]};
            *(f16x8*)(sm + OKT + d * 80 + ((16 * rb) ^ sig)) = q8;
        }
        if (more) {
            #pragma unroll
            for (int i = 0; i < 8; ++i) hvB[i] = hvA[i];
        }
    }

    __syncthreads();   // KT(NCH-1) written in last phase C

    // ---- final PV(NCH-1) ----
    {
        const int qb2 = (NCH - 1) & 1;
        const uint4* fp = (const uint4*)(sm + OFLG + 32 * qb2);
        uint4 f0 = fp[0], f1 = fp[1];
        bool doR = (f0.x | f0.y | f0.z | f0.w | f1.x | f1.y | f1.z | f1.w) != 0;
        f16x8 bP[4];
        #pragma unroll
        for (int tt = 0; tt < 4; ++tt)
            bP[tt] = *(const f16x8*)(sm + OP + OPSZ * qb2 + (16 * tt + li) * 80 + 16 * gi);
        if (doR) {
            float av[4];
            #pragma unroll
            for (int tt = 0; tt < 4; ++tt)
                av[tt] = *(const float*)(sm + OAL + 256 * qb2 + 4 * (16 * tt + li));
            #pragma unroll
            for (int md = 0; md < 4; ++md)
                #pragma unroll
                for (int tt = 0; tt < 4; ++tt)
                    #pragma unroll
                    for (int r = 0; r < 4; ++r) ctx[md][tt][r] *= av[tt];
        }
        #pragma unroll
        for (int md = 0; md < 4; ++md) {
            int dv = 64 * wv + 16 * md + li;
            int sig = ((dv >> 3) & 3) << 4;
            f16x8 a = *(const f16x8*)(sm + OKT + dv * 80 + ((16 * gi) ^ sig));
            #pragma unroll
            for (int tt = 0; tt < 4; ++tt)
                ctx[md][tt] = __builtin_amdgcn_mfma_f32_16x16x32_f16(a, bP[tt], ctx[md][tt], 0, 0, 0);
        }
    }

    // ---- epilogue: l-normalize + context writes + dec passthrough ----
    if (erq == 0) *(float*)(sm + OLL + 4 * tcol) = lrun;
    __syncthreads();
    float inv[4];
    #pragma unroll
    for (int tt = 0; tt < 4; ++tt)
        inv[tt] = 1.0f / *(const float*)(sm + OLL + 4 * (16 * tt + li));
    #pragma unroll
    for (int md = 0; md < 4; ++md)
        #pragma unroll
        for (int tt = 0; tt < 4; ++tt) {
            int t = t0 + 16 * tt + li;
            int d = 64 * wv + 16 * md + 4 * gi;
            float4 o;
            o.x = ctx[md][tt][0] * inv[tt];
            o.y = ctx[md][tt][1] * inv[tt];
            o.z = ctx[md][tt][2] * inv[tt];
            o.w = ctx[md][tt][3] * inv[tt];
            *(float4*)(outB + (size_t)t * (2 * DD) + DD + d) = o;
        }
    #pragma unroll
    for (int it = 0; it < TBLK * (DD / 4) / 512; ++it) {
        int i = tid + it * 512;
        int t = i >> 7, cc = i & 127;
        float4 q = ((const float4*)(decB + (size_t)(t0 + t) * DD))[cc];
        ((float4*)(outB + (size_t)(t0 + t) * (2 * DD)))[cc] = q;
    }
}

extern "C" void kernel_launch(void* const* d_in, const int* in_sizes, int n_in,
                              void* d_out, int out_size, void* d_ws, size_t ws_size,
                              hipStream_t stream) {
    const float* enc = (const float*)d_in[0];
    const float* dec = (const float*)d_in[1];
    float* out = (float*)d_out;
    dim3 grid(NB * (TD / TBLK));   // 256 blocks: b = bid&7 (XCD pin), ttile = bid>>3
    dim3 block(512);
    attn_fused<<<grid, block, 0, stream>>>(enc, dec, out);
}

// Round 9
// 136.512 us; speedup vs baseline: 2.8315x; 1.0630x over previous
//
#include <hip/hip_runtime.h>

// Fused cross-attention: out = concat(dec, softmax_e(enc·dec^T)^T-weighted enc)
// B=8, T_enc=T_dec=2048, D=512, fp32 in/out.
// R9: R8 + softmax fast path: per-lane partial l (epilogue reduce), local
//     max-check + ballot -> cross-lane max reduce only when running max grows
//     (T13). Fast path has ZERO shfl ops -> removes the serial ds-latency
//     chain that bounded phase B. Everything else identical to R8.

typedef _Float16 f16;
typedef f16 f16x8 __attribute__((ext_vector_type(8)));
typedef f16 f16x4 __attribute__((ext_vector_type(4)));
typedef float f32x4 __attribute__((ext_vector_type(4)));

#define NB 8
#define TE 2048
#define TD 2048
#define DD 512
#define TBLK 64
#define EBLK 32
#define NCH (TE / EBLK)

// LDS layout (bytes) — audited: end 121664 < 163840
#define OKHI 0          // [32 e][512 d] f16 = 32768B, 1024B swizzled rows (QK A)
#define OKT  32768      // [512 d][40 e] f16 = 40960B, 80B rows, sig-swizzled (PV A)
#define OS4  73728      // 4 kq x [64 t][36 e] f32 = 36864B (144B rows)
#define OP   110592     // 2 x [64 t][40 e] f16 = 10240B, 80B rows
#define OPSZ 5120
#define OAL  120832     // 2 x 64 f32 alpha
#define OLL  121344     // 64 f32 l
#define OFLG 121600     // 2 x 8 u32 rescale flags
#define SMEM_BYTES 121664

__device__ __forceinline__ int swz1k(int row, int byteInRow) {
    return row * 1024 + (byteInRow ^ ((row & 7) << 4));
}

__global__ __launch_bounds__(512, 2)
void attn_fused(const float* __restrict__ enc, const float* __restrict__ dec,
                float* __restrict__ out) {
    __shared__ __align__(16) char sm[SMEM_BYTES];
    const int tid  = threadIdx.x;
    const int b    = blockIdx.x & 7;          // XCD-pinned batch
    const int t0   = (blockIdx.x >> 3) * TBLK;
    const int lane = tid & 63;
    const int wv   = tid >> 6;
    const int li   = lane & 15;
    const int gi   = lane >> 4;
    const int tq   = wv & 1;                  // t-half: rows 32tq..32tq+31
    const int kq   = wv >> 1;                 // k-slice: d in [128kq, 128kq+128)
    const float L2E = 1.44269504088896f;

    const float* encB = enc + (size_t)b * TE * DD;
    const float* decB = dec + (size_t)b * TD * DD;
    float*       outB = out + (size_t)b * TD * (2 * DD);

    // staging map: c4 = d-quad 0..127, rb = e-octet 0..3 (e rows 8rb..8rb+7)
    const int c4 = tid & 127;
    const int rb = tid >> 7;

    // ---- issue K0 loads ----
    f32x4 st[8];
    #pragma unroll
    for (int i = 0; i < 8; ++i)
        st[i] = *(const f32x4*)(encB + (size_t)(8 * rb + i) * DD + 4 * c4);

    // ---- Q fragments (f16) direct from global ----
    f16x8 qF[4][2];
    #pragma unroll
    for (int kk = 0; kk < 4; ++kk)
        #pragma unroll
        for (int tl = 0; tl < 2; ++tl) {
            const float* qp = decB + (size_t)(t0 + 32 * tq + 16 * tl + li) * DD
                            + 128 * kq + 32 * kk + 8 * gi;
            f32x4 q0 = *(const f32x4*)qp;
            f32x4 q1 = *(const f32x4*)(qp + 4);
            f16x8 h;
            #pragma unroll
            for (int j = 0; j < 4; ++j) { h[j] = (f16)q0[j]; h[4 + j] = (f16)q1[j]; }
            qF[kk][tl] = h;
        }

    // ---- cvt K0 -> hvB + Khi-write(0); KT(0) written in iter 0 phase C ----
    f16x4 hvB[8];
    #pragma unroll
    for (int i = 0; i < 8; ++i) {
        f16x4 h4 = {(f16)st[i][0], (f16)st[i][1], (f16)st[i][2], (f16)st[i][3]};
        hvB[i] = h4;
        *(f16x4*)(sm + OKHI + swz1k(8 * rb + i, 8 * c4)) = h4;
    }
    // issue K1 loads
    #pragma unroll
    for (int i = 0; i < 8; ++i)
        st[i] = *(const f32x4*)(encB + (size_t)(EBLK + 8 * rb + i) * DD + 4 * c4);
    __syncthreads();

    // softmax ownership: wave owns t-cols [8wv, 8wv+8); 8 lanes/col, 4 e/lane
    const int cq   = lane & 7;
    const int erq  = lane >> 3;               // 0..7 -> e rows 4erq..4erq+3
    const int tcol = 8 * wv + cq;
    float mrun = -1.0e30f;
    float lpart = 0.0f;                       // per-lane partial of l (4 e-slots)

    f32x4 ctx[4][4];                          // d [64wv,64wv+64) x t [0,64)
    #pragma unroll
    for (int md = 0; md < 4; ++md)
        #pragma unroll
        for (int tt = 0; tt < 4; ++tt)
            ctx[md][tt] = (f32x4){0.f, 0.f, 0.f, 0.f};

    for (int ch = 0; ch < NCH; ++ch) {
        const int pb = ch & 1;
        const int qb = pb ^ 1;
        const bool doPV = (ch > 0);
        const bool more = (ch + 1 < NCH);

        // ---- phase A: QK(ch), S4 partial writes ----
        f32x4 sacc[2][2];
        #pragma unroll
        for (int et = 0; et < 2; ++et)
            #pragma unroll
            for (int tl = 0; tl < 2; ++tl)
                sacc[et][tl] = (f32x4){0.f, 0.f, 0.f, 0.f};
        __builtin_amdgcn_s_setprio(1);
        #pragma unroll
        for (int kk = 0; kk < 4; ++kk) {
            int cb = 256 * kq + 64 * kk + 16 * gi;
            f16x8 aF[2];
            #pragma unroll
            for (int et = 0; et < 2; ++et)
                aF[et] = *(const f16x8*)(sm + OKHI + swz1k(16 * et + li, cb));
            #pragma unroll
            for (int et = 0; et < 2; ++et)
                #pragma unroll
                for (int tl = 0; tl < 2; ++tl)
                    sacc[et][tl] = __builtin_amdgcn_mfma_f32_16x16x32_f16(aF[et], qF[kk][tl], sacc[et][tl], 0, 0, 0);
        }
        __builtin_amdgcn_s_setprio(0);
        #pragma unroll
        for (int et = 0; et < 2; ++et)
            #pragma unroll
            for (int tl = 0; tl < 2; ++tl)
                *(f32x4*)(sm + OS4 + kq * 9216 + (32 * tq + 16 * tl + li) * 144
                          + (16 * et + 4 * gi) * 4) = sacc[et][tl];
        __syncthreads();                                   // B1

        // ---- phase B: softmax(ch) ∥ PV(ch-1) ∥ Khi(ch+1) ∥ loads(ch+2) ----
        // S-reads first (start latency earliest)
        f32x4 s4 = (f32x4){0.f, 0.f, 0.f, 0.f};
        #pragma unroll
        for (int bu = 0; bu < 4; ++bu)
            s4 += *(const f32x4*)(sm + OS4 + bu * 9216 + tcol * 144 + 16 * erq);

        bool doR = false;
        f16x8 bP[4];
        if (doPV) {
            const uint4* fp = (const uint4*)(sm + OFLG + 32 * qb);
            uint4 f0 = fp[0], f1 = fp[1];
            doR = (f0.x | f0.y | f0.z | f0.w | f1.x | f1.y | f1.z | f1.w) != 0;
            #pragma unroll
            for (int tt = 0; tt < 4; ++tt)
                bP[tt] = *(const f16x8*)(sm + OP + OPSZ * qb + (16 * tt + li) * 80 + 16 * gi);
        }
        // softmax(ch): fast path has zero cross-lane ops
        {
            float pml = fmaxf(fmaxf(s4[0], s4[1]), fmaxf(s4[2], s4[3]));
            bool trip = pml > mrun + 8.0f;                 // T13 defer-max
            unsigned long long bal = __ballot(trip);
            float alpha = 1.0f;
            if (bal != 0ULL) {                             // wave-uniform slow path
                float pm = pml;
                pm = fmaxf(pm, __shfl_xor(pm, 8));
                pm = fmaxf(pm, __shfl_xor(pm, 16));
                pm = fmaxf(pm, __shfl_xor(pm, 32));
                float mnew = fmaxf(mrun, pm);
                alpha = exp2f((mrun - mnew) * L2E);
                lpart *= alpha;
                mrun = mnew;
            }
            f32x4 p4;
            #pragma unroll
            for (int j = 0; j < 4; ++j) p4[j] = exp2f((s4[j] - mrun) * L2E);
            lpart += p4[0] + p4[1] + p4[2] + p4[3];
            f16x4 pw = {(f16)p4[0], (f16)p4[1], (f16)p4[2], (f16)p4[3]};
            *(f16x4*)(sm + OP + OPSZ * pb + tcol * 80 + 8 * erq) = pw;
            if (erq == 0) *(float*)(sm + OAL + 256 * pb + 4 * tcol) = alpha;
            if (lane == 0) *(unsigned*)(sm + OFLG + 32 * pb + 4 * wv) = (bal != 0ULL) ? 1u : 0u;
        }
        // PV(ch-1): KT holds chunk ch-1 (written in phase C of iter ch-1)
        if (doPV) {
            if (doR) {
                float av[4];
                #pragma unroll
                for (int tt = 0; tt < 4; ++tt)
                    av[tt] = *(const float*)(sm + OAL + 256 * qb + 4 * (16 * tt + li));
                #pragma unroll
                for (int md = 0; md < 4; ++md)
                    #pragma unroll
                    for (int tt = 0; tt < 4; ++tt)
                        #pragma unroll
                        for (int r = 0; r < 4; ++r) ctx[md][tt][r] *= av[tt];
            }
            __builtin_amdgcn_s_setprio(1);
            #pragma unroll
            for (int md = 0; md < 4; ++md) {
                int dv = 64 * wv + 16 * md + li;
                int sig = ((dv >> 3) & 3) << 4;
                f16x8 a = *(const f16x8*)(sm + OKT + dv * 80 + ((16 * gi) ^ sig));
                #pragma unroll
                for (int tt = 0; tt < 4; ++tt)
                    ctx[md][tt] = __builtin_amdgcn_mfma_f32_16x16x32_f16(a, bP[tt], ctx[md][tt], 0, 0, 0);
            }
            __builtin_amdgcn_s_setprio(0);
        }
        // cvt st(ch+1) -> hvA + Khi-write(ch+1); issue loads(ch+2)
        f16x4 hvA[8];
        if (more) {
            #pragma unroll
            for (int i = 0; i < 8; ++i) {
                f16x4 h4 = {(f16)st[i][0], (f16)st[i][1], (f16)st[i][2], (f16)st[i][3]};
                hvA[i] = h4;
                *(f16x4*)(sm + OKHI + swz1k(8 * rb + i, 8 * c4)) = h4;
            }
            if (ch + 2 < NCH) {
                const float* src = encB + (size_t)(ch + 2) * EBLK * DD;
                #pragma unroll
                for (int i = 0; i < 8; ++i)
                    st[i] = *(const f32x4*)(src + (size_t)(8 * rb + i) * DD + 4 * c4);
            }
        }
        __syncthreads();                                   // B2
        // ---- phase C: KT-write(ch) from hvB ----
        #pragma unroll
        for (int k = 0; k < 4; ++k) {
            int d = 4 * c4 + k;
            int sig = ((d >> 3) & 3) << 4;
            f16x8 q8 = {hvB[0][k], hvB[1][k], hvB[2][k], hvB[3][k],
                        hvB[4][k], hvB[5][k], hvB[6][k], hvB[7][k]};
            *(f16x8*)(sm + OKT + d * 80 + ((16 * rb) ^ sig)) = q8;
        }
        if (more) {
            #pragma unroll
            for (int i = 0; i < 8; ++i) hvB[i] = hvA[i];
        }
    }

    __syncthreads();   // KT(NCH-1) written in last phase C

    // ---- final PV(NCH-1) ----
    {
        const int qb2 = (NCH - 1) & 1;
        const uint4* fp = (const uint4*)(sm + OFLG + 32 * qb2);
        uint4 f0 = fp[0], f1 = fp[1];
        bool doR = (f0.x | f0.y | f0.z | f0.w | f1.x | f1.y | f1.z | f1.w) != 0;
        f16x8 bP[4];
        #pragma unroll
        for (int tt = 0; tt < 4; ++tt)
            bP[tt] = *(const f16x8*)(sm + OP + OPSZ * qb2 + (16 * tt + li) * 80 + 16 * gi);
        if (doR) {
            float av[4];
            #pragma unroll
            for (int tt = 0; tt < 4; ++tt)
                av[tt] = *(const float*)(sm + OAL + 256 * qb2 + 4 * (16 * tt + li));
            #pragma unroll
            for (int md = 0; md < 4; ++md)
                #pragma unroll
                for (int tt = 0; tt < 4; ++tt)
                    #pragma unroll
                    for (int r = 0; r < 4; ++r) ctx[md][tt][r] *= av[tt];
        }
        #pragma unroll
        for (int md = 0; md < 4; ++md) {
            int dv = 64 * wv + 16 * md + li;
            int sig = ((dv >> 3) & 3) << 4;
            f16x8 a = *(const f16x8*)(sm + OKT + dv * 80 + ((16 * gi) ^ sig));
            #pragma unroll
            for (int tt = 0; tt < 4; ++tt)
                ctx[md][tt] = __builtin_amdgcn_mfma_f32_16x16x32_f16(a, bP[tt], ctx[md][tt], 0, 0, 0);
        }
    }

    // ---- epilogue: reduce per-lane l partials once, normalize, write ----
    {
        float ps = lpart;
        ps += __shfl_xor(ps, 8);
        ps += __shfl_xor(ps, 16);
        ps += __shfl_xor(ps, 32);
        if (erq == 0) *(float*)(sm + OLL + 4 * tcol) = ps;
    }
    __syncthreads();
    float inv[4];
    #pragma unroll
    for (int tt = 0; tt < 4; ++tt)
        inv[tt] = 1.0f / *(const float*)(sm + OLL + 4 * (16 * tt + li));
    #pragma unroll
    for (int md = 0; md < 4; ++md)
        #pragma unroll
        for (int tt = 0; tt < 4; ++tt) {
            int t = t0 + 16 * tt + li;
            int d = 64 * wv + 16 * md + 4 * gi;
            float4 o;
            o.x = ctx[md][tt][0] * inv[tt];
            o.y = ctx[md][tt][1] * inv[tt];
            o.z = ctx[md][tt][2] * inv[tt];
            o.w = ctx[md][tt][3] * inv[tt];
            *(float4*)(outB + (size_t)t * (2 * DD) + DD + d) = o;
        }
    #pragma unroll
    for (int it = 0; it < TBLK * (DD / 4) / 512; ++it) {
        int i = tid + it * 512;
        int t = i >> 7, cc = i & 127;
        float4 q = ((const float4*)(decB + (size_t)(t0 + t) * DD))[cc];
        ((float4*)(outB + (size_t)(t0 + t) * (2 * DD)))[cc] = q;
    }
}

extern "C" void kernel_launch(void* const* d_in, const int* in_sizes, int n_in,
                              void* d_out, int out_size, void* d_ws, size_t ws_size,
                              hipStream_t stream) {
    const float* enc = (const float*)d_in[0];
    const float* dec = (const float*)d_in[1];
    float* out = (float*)d_out;
    dim3 grid(NB * (TD / TBLK));   // 256 blocks: b = bid&7 (XCD pin), ttile = bid>>3
    dim3 block(512);
    attn_fused<<<grid, block, 0, stream>>>(enc, dec, out);
}